// Round 1
// baseline (2475.863 us; speedup 1.0000x reference)
//
#include <hip/hip_runtime.h>

using bf16   = __bf16;
using bf16x8 = __bf16 __attribute__((ext_vector_type(8)));
using f32x4  = float  __attribute__((ext_vector_type(4)));

// B=1024, T=64, F=256, H=1024, C=2
// Chunking: 4 chunks of 16 timesteps, with +1 lookahead slice for gamma_h.

__device__ __forceinline__ float sigm(float x) { return 1.f / (1.f + __expf(-x)); }
__device__ __forceinline__ float tanh_fast(float x) {
  float e = __expf(2.f * x);
  return 1.f - 2.f / (e + 1.f);
}

// ---------------------------------------------------------------------------
// prep: per (tl,b,f): Dbf (bf16 time-major), XR = [x_replaced | m] (bf16)
// ---------------------------------------------------------------------------
__global__ void prep_kernel(const float* __restrict__ X, const float* __restrict__ Msk,
                            const float* __restrict__ D, const float* __restrict__ Mean,
                            const float* __restrict__ L, const float* __restrict__ w_gx,
                            const float* __restrict__ b_gx,
                            bf16* __restrict__ XR, bf16* __restrict__ Dbf,
                            int c, int nsl) {
  int i = blockIdx.x * 256 + threadIdx.x;
  if (i >= nsl * (1 << 18)) return;            // nsl * B * F
  int f = i & 255, b = (i >> 8) & 1023, tl = i >> 18;
  int t = c * 16 + tl;                          // t < 64 guaranteed by nsl
  size_t g = ((size_t)b << 14) + ((size_t)t << 8) + f;  // X[b][t][f]
  float d = D[g];
  Dbf[i] = (bf16)d;                             // i == (tl*1024+b)*256+f
  float gx = __expf(-fmaxf(d * w_gx[f] + b_gx[f], 0.f));
  float xh = gx * L[g] + (1.f - gx) * Mean[(size_t)b * 256 + f];
  float m  = Msk[g];
  float xr = m * X[g] + (1.f - m) * xh;
  size_t xo = (((size_t)tl * 1024 + b) << 9) + f;  // [tl][b][512]
  XR[xo]       = (bf16)xr;
  XR[xo + 256] = (bf16)m;
}

// ---------------------------------------------------------------------------
// wprep: combined GRU weights Wc[4096][1536] (n = g*1024+j), Wg bf16, bias4
// ---------------------------------------------------------------------------
__global__ void wprep_kernel(const float* __restrict__ w_ih, const float* __restrict__ w_hh,
                             const float* __restrict__ b_ih, const float* __restrict__ b_hh,
                             const float* __restrict__ w_gh,
                             bf16* __restrict__ Wc, bf16* __restrict__ Wg,
                             float* __restrict__ bias4) {
  int i = blockIdx.x * 256 + threadIdx.x;
  if (i < 4096 * 1536) {           // Wc
    int n = i / 1536, k = i - n * 1536;
    int g = n >> 10, j = n & 1023;
    int kh = k - 512;
    float v;
    if (g == 3) {
      v = (k < 512) ? 0.f : w_hh[(size_t)(2048 + j) * 1024 + kh];
    } else {
      int r = g * 1024 + j;
      if (k < 256)      v = w_ih[(size_t)r * 1536 + k];
      else if (k < 512) v = w_ih[(size_t)r * 1536 + 1280 + (k - 256)];
      else {
        v = w_ih[(size_t)r * 1536 + 256 + kh];
        if (g < 2) v += w_hh[(size_t)r * 1024 + kh];
      }
    }
    Wc[i] = (bf16)v;
  } else if (i < 4096 * 1536 + 262144) {   // Wg
    int q = i - 4096 * 1536;
    Wg[q] = (bf16)w_gh[q];
  } else if (i < 4096 * 1536 + 262144 + 4096) {  // bias4 [g][j]
    int q = i - (4096 * 1536 + 262144);
    int g = q >> 10, j = q & 1023;
    float v;
    if (g == 0)      v = b_ih[j] + b_hh[j];
    else if (g == 1) v = b_ih[1024 + j] + b_hh[1024 + j];
    else if (g == 2) v = b_ih[2048 + j];
    else             v = b_hh[2048 + j];
    bias4[q] = v;
  }
}

// ---------------------------------------------------------------------------
// gammah: GH[m][n] = exp(-relu(Dbf[m][:] . Wg[n][:] + b_gh[n])), M = nsl*1024
// 128x128 tile, 4 waves (2x2), BK=64, K=256, XOR-swizzled LDS
// ---------------------------------------------------------------------------
__global__ __launch_bounds__(256) void gammah_kernel(const bf16* __restrict__ Dbf,
                                                     const bf16* __restrict__ Wg,
                                                     const float* __restrict__ b_gh,
                                                     bf16* __restrict__ GH) {
  __shared__ char As[16384];
  __shared__ char Bs[16384];
  int tid = threadIdx.x, lane = tid & 63, wid = tid >> 6;
  int wr = wid >> 1, wc = wid & 1;
  int mb = blockIdx.x, nb = blockIdx.y;
  int r0 = tid >> 3, k8 = tid & 7;

  f32x4 acc[4][4];
#pragma unroll
  for (int a = 0; a < 4; ++a)
#pragma unroll
    for (int b = 0; b < 4; ++b)
#pragma unroll
      for (int q = 0; q < 4; ++q) acc[a][b][q] = 0.f;

  for (int kt = 0; kt < 4; ++kt) {
#pragma unroll
    for (int rr = 0; rr < 4; ++rr) {
      int row = r0 + rr * 32;
      bf16x8 va = *(const bf16x8*)((const char*)Dbf +
                    ((size_t)(mb * 128 + row) * 256 + kt * 64) * 2 + k8 * 16);
      *(bf16x8*)(As + row * 128 + ((k8 ^ (row & 7)) * 16)) = va;
      bf16x8 vb = *(const bf16x8*)((const char*)Wg +
                    ((size_t)(nb * 128 + row) * 256 + kt * 64) * 2 + k8 * 16);
      *(bf16x8*)(Bs + row * 128 + ((k8 ^ (row & 7)) * 16)) = vb;
    }
    __syncthreads();
#pragma unroll
    for (int kk = 0; kk < 2; ++kk) {
      int kb = kk * 64 + ((lane >> 4) * 16);
      bf16x8 af[4], bf_[4];
#pragma unroll
      for (int mf = 0; mf < 4; ++mf) {
        int row = wr * 64 + mf * 16 + (lane & 15);
        af[mf] = *(const bf16x8*)(As + ((row * 128 + kb) ^ ((row & 7) << 4)));
      }
#pragma unroll
      for (int nf = 0; nf < 4; ++nf) {
        int nl = wc * 64 + nf * 16 + (lane & 15);
        bf_[nf] = *(const bf16x8*)(Bs + ((nl * 128 + kb) ^ ((nl & 7) << 4)));
      }
#pragma unroll
      for (int mf = 0; mf < 4; ++mf)
#pragma unroll
        for (int nf = 0; nf < 4; ++nf)
          acc[mf][nf] = __builtin_amdgcn_mfma_f32_16x16x32_bf16(af[mf], bf_[nf], acc[mf][nf], 0, 0, 0);
    }
    __syncthreads();
  }
  // epilogue
#pragma unroll
  for (int nf = 0; nf < 4; ++nf) {
    int n = nb * 128 + wc * 64 + nf * 16 + (lane & 15);
    float bg = b_gh[n];
#pragma unroll
    for (int mf = 0; mf < 4; ++mf)
#pragma unroll
      for (int reg = 0; reg < 4; ++reg) {
        int m = mb * 128 + wr * 64 + mf * 16 + (lane >> 4) * 4 + reg;
        float v = acc[mf][nf][reg] + bg;
        GH[(size_t)m * 1024 + n] = (bf16)__expf(-fmaxf(v, 0.f));
      }
  }
}

// ---------------------------------------------------------------------------
// step: one GRU-D timestep. GEMM A=[XR_t | hdec_bf16] (1024x1536),
// Wc (1536 x 4096, n=g*1024+j), fused GRU epilogue + next-step decay.
// ---------------------------------------------------------------------------
__global__ __launch_bounds__(256) void step_kernel(
    const bf16* __restrict__ xr_t,     // [1024][512]
    const bf16* __restrict__ hbf,      // [1024][1024] decayed h (bf16)
    const float* __restrict__ hf,      // [1024][1024] decayed h (f32)
    const bf16* __restrict__ Wc,       // [4096][1536]
    const float* __restrict__ bias4,   // [4][1024]
    const bf16* __restrict__ gh_next,  // [1024][1024] gamma for t+1
    int is_last,
    float* __restrict__ hf_next, bf16* __restrict__ hbf_next) {
  __shared__ char As[16384];
  __shared__ char Bs[16384];
  int tid = threadIdx.x, lane = tid & 63, wid = tid >> 6;
  int wr = wid >> 1, wc = wid & 1;
  int mb = blockIdx.x, nb = blockIdx.y;
  int jb = nb * 32;
  int r0 = tid >> 3, k8 = tid & 7;

  f32x4 acc[4][4];   // acc[mf][gate]
#pragma unroll
  for (int a = 0; a < 4; ++a)
#pragma unroll
    for (int b = 0; b < 4; ++b)
#pragma unroll
      for (int q = 0; q < 4; ++q) acc[a][b][q] = 0.f;

  for (int kt = 0; kt < 24; ++kt) {
    const char* asrc;
    size_t arstride;
    if (kt < 8) { asrc = (const char*)xr_t + ((size_t)(mb * 128) * 512 + kt * 64) * 2;        arstride = 1024; }
    else        { asrc = (const char*)hbf  + ((size_t)(mb * 128) * 1024 + (kt - 8) * 64) * 2; arstride = 2048; }
#pragma unroll
    for (int rr = 0; rr < 4; ++rr) {
      int row = r0 + rr * 32;
      bf16x8 v = *(const bf16x8*)(asrc + (size_t)row * arstride + k8 * 16);
      *(bf16x8*)(As + row * 128 + ((k8 ^ (row & 7)) * 16)) = v;
    }
#pragma unroll
    for (int rr = 0; rr < 4; ++rr) {
      int nl = r0 + rr * 32;
      int n = ((nl >> 5) << 10) + jb + (nl & 31);   // g*1024 + jb + jj
      bf16x8 v = *(const bf16x8*)((const char*)Wc + ((size_t)n * 1536 + kt * 64) * 2 + k8 * 16);
      *(bf16x8*)(Bs + nl * 128 + ((k8 ^ (nl & 7)) * 16)) = v;
    }
    __syncthreads();
#pragma unroll
    for (int kk = 0; kk < 2; ++kk) {
      int kb = kk * 64 + ((lane >> 4) * 16);
      bf16x8 af[4], bf_[4];
#pragma unroll
      for (int mf = 0; mf < 4; ++mf) {
        int row = wr * 64 + mf * 16 + (lane & 15);
        af[mf] = *(const bf16x8*)(As + ((row * 128 + kb) ^ ((row & 7) << 4)));
      }
#pragma unroll
      for (int g = 0; g < 4; ++g) {
        int nl = g * 32 + wc * 16 + (lane & 15);
        bf_[g] = *(const bf16x8*)(Bs + ((nl * 128 + kb) ^ ((nl & 7) << 4)));
      }
#pragma unroll
      for (int mf = 0; mf < 4; ++mf)
#pragma unroll
        for (int g = 0; g < 4; ++g)
          acc[mf][g] = __builtin_amdgcn_mfma_f32_16x16x32_bf16(af[mf], bf_[g], acc[mf][g], 0, 0, 0);
    }
    __syncthreads();
  }

  // fused GRU epilogue: all 4 gates for (b,j) live in this lane's acc[mf][*]
  int j = jb + wc * 16 + (lane & 15);
  float br = bias4[j], bz = bias4[1024 + j], bn = bias4[2048 + j], bh = bias4[3072 + j];
#pragma unroll
  for (int mf = 0; mf < 4; ++mf) {
#pragma unroll
    for (int reg = 0; reg < 4; ++reg) {
      int brow = mb * 128 + wr * 64 + mf * 16 + (lane >> 4) * 4 + reg;
      float pr  = acc[mf][0][reg] + br;
      float pz  = acc[mf][1][reg] + bz;
      float pin = acc[mf][2][reg] + bn;
      float phn = acc[mf][3][reg] + bh;
      float r = sigm(pr);
      float z = sigm(pz);
      float nn = tanh_fast(pin + r * phn);
      float hold = hf[(size_t)brow * 1024 + j];
      float hnew = (1.f - z) * nn + z * hold;
      float gam = 1.f;
      if (!is_last) gam = (float)gh_next[(size_t)brow * 1024 + j];
      float hd = hnew * gam;
      hf_next[(size_t)brow * 1024 + j]  = hd;
      hbf_next[(size_t)brow * 1024 + j] = (bf16)hd;
    }
  }
}

// ---------------------------------------------------------------------------
// classifier + softmax: one wave per batch row
// ---------------------------------------------------------------------------
__global__ void cls_kernel(const float* __restrict__ h, const float* __restrict__ w_cls,
                           const float* __restrict__ b_cls, float* __restrict__ out) {
  int wid = threadIdx.x >> 6, lane = threadIdx.x & 63;
  int b = blockIdx.x * 4 + wid;
  const float* hb = h + (size_t)b * 1024;
  float a0 = 0.f, a1 = 0.f;
#pragma unroll
  for (int e = 0; e < 16; ++e) {
    int i = e * 64 + lane;
    float hv = hb[i];
    a0 += hv * w_cls[i];
    a1 += hv * w_cls[1024 + i];
  }
  for (int off = 32; off; off >>= 1) {
    a0 += __shfl_down(a0, off);
    a1 += __shfl_down(a1, off);
  }
  if (lane == 0) {
    float l0 = a0 + b_cls[0], l1 = a1 + b_cls[1];
    float mx = fmaxf(l0, l1);
    float e0 = __expf(l0 - mx), e1 = __expf(l1 - mx);
    float s = e0 + e1;
    out[b * 2]     = e0 / s;
    out[b * 2 + 1] = e1 / s;
  }
}

// ---------------------------------------------------------------------------
extern "C" void kernel_launch(void* const* d_in, const int* in_sizes, int n_in,
                              void* d_out, int out_size, void* d_ws, size_t ws_size,
                              hipStream_t stream) {
  const float* X     = (const float*)d_in[0];
  const float* Msk   = (const float*)d_in[1];
  const float* D     = (const float*)d_in[2];
  const float* Mean  = (const float*)d_in[3];
  const float* L     = (const float*)d_in[4];
  const float* w_gh  = (const float*)d_in[5];
  const float* b_gh  = (const float*)d_in[6];
  const float* w_gx  = (const float*)d_in[7];
  const float* b_gx  = (const float*)d_in[8];
  const float* w_ih  = (const float*)d_in[9];
  const float* w_hh  = (const float*)d_in[10];
  const float* b_ih  = (const float*)d_in[11];
  const float* b_hh  = (const float*)d_in[12];
  const float* w_cls = (const float*)d_in[13];
  const float* b_cls = (const float*)d_in[14];

  char* w = (char*)d_ws;
  bf16*  XR    = (bf16*)(w);                       // 17*1024*512*2  = 17825792
  bf16*  Dbf   = (bf16*)(w + 17825792);            // 17*1024*256*2  = 8912896
  bf16*  GH    = (bf16*)(w + 26738688);            // 17*1024*1024*2 = 35651584
  bf16*  Wc    = (bf16*)(w + 62390272);            // 4096*1536*2    = 12582912
  bf16*  Wg    = (bf16*)(w + 74973184);            // 1024*256*2     = 524288
  float* bias4 = (float*)(w + 75497472);           // 4096*4         = 16384
  float* hf0   = (float*)(w + 75513856);           // 1024*1024*4
  float* hf1   = (float*)(w + 75513856 + 4194304);
  bf16*  hb0   = (bf16*)(w + 83902464);            // 1024*1024*2
  bf16*  hb1   = (bf16*)(w + 83902464 + 2097152);
  float* hf[2] = {hf0, hf1};
  bf16*  hb[2] = {hb0, hb1};

  hipMemsetAsync(hf0, 0, 4194304, stream);
  hipMemsetAsync(hb0, 0, 2097152, stream);
  wprep_kernel<<<25616, 256, 0, stream>>>(w_ih, w_hh, b_ih, b_hh, w_gh, Wc, Wg, bias4);

  int t = 0;
  for (int c = 0; c < 4; ++c) {
    int nsl = (c < 3) ? 17 : 16;
    prep_kernel<<<nsl * 1024, 256, 0, stream>>>(X, Msk, D, Mean, L, w_gx, b_gx, XR, Dbf, c, nsl);
    gammah_kernel<<<dim3(nsl * 8, 8), 256, 0, stream>>>(Dbf, Wg, b_gh, GH);
    for (int tl = 0; tl < 16; ++tl, ++t) {
      int cur = t & 1, nxt = cur ^ 1;
      step_kernel<<<dim3(8, 32), 256, 0, stream>>>(
          XR + (size_t)tl * 1024 * 512, hb[cur], hf[cur], Wc, bias4,
          GH + (size_t)(tl + 1) * 1024 * 1024, (t == 63) ? 1 : 0, hf[nxt], hb[nxt]);
    }
  }
  cls_kernel<<<256, 256, 0, stream>>>(hf[0], w_cls, b_cls, (float*)d_out);
}

// Round 2
// 2084.818 us; speedup vs baseline: 1.1876x; 1.1876x over previous
//
#include <hip/hip_runtime.h>

using bf16   = __bf16;
using bf16x8 = __bf16 __attribute__((ext_vector_type(8)));
using f32x4  = float  __attribute__((ext_vector_type(4)));

// B=1024, T=64, F=256, H=1024, C=2
// ws layout (bytes):
//  XRs   @0          16,777,216   [16 slices][1024 b][512 k]  pre-swizzled bf16
//  Dbfs  @16777216    8,912,896   [17][1024][256]             pre-swizzled bf16
//  GH    @25690112   35,651,584   [17][1024][1024]            plain bf16
//  WcX2  @61341696    4,194,304   [nb32][kt8][nl128][64]      tiled bf16
//  WcH2  @65536000    8,388,608   [nb32][kt16][nl128][64]     tiled bf16
//  Wgs   @73924608      524,288   [nb8][kt4][nl128][64]       tiled bf16
//  bias4 @74448896       16,384   [4][1024] f32
//  hf0/1 @74465280    8,388,608   f32 state x2
//  hb0/1 @82853888    4,194,304   bf16 pre-swizzled state x2
//  Gi    @87048192    GCH*8,388,608  [GCH][1024][4096] bf16

__device__ __forceinline__ float sigm(float x) { return 1.f / (1.f + __expf(-x)); }
__device__ __forceinline__ float tanh_fast(float x) {
  float e = __expf(2.f * x);
  return 1.f - 2.f / (e + 1.f);
}

#define GLL16(gsrc, ldst)                                                              \
  __builtin_amdgcn_global_load_lds((const __attribute__((address_space(1))) void*)(gsrc), \
                                   (__attribute__((address_space(3))) void*)(ldst), 16, 0, 0)

// ---------------------------------------------------------------------------
// prep: writes pre-swizzled XRs ([xr|m], k XOR (b&7)<<3) and Dbfs
// ---------------------------------------------------------------------------
__global__ void prep_kernel(const float* __restrict__ X, const float* __restrict__ Msk,
                            const float* __restrict__ D, const float* __restrict__ Mean,
                            const float* __restrict__ L, const float* __restrict__ w_gx,
                            const float* __restrict__ b_gx,
                            bf16* __restrict__ XRs, bf16* __restrict__ Dbfs,
                            int c, int nsl) {
  int i = blockIdx.x * 256 + threadIdx.x;
  if (i >= (nsl << 18)) return;
  int f = i & 255, b = (i >> 8) & 1023, tl = i >> 18;
  int t = c * 16 + tl;
  size_t g = ((size_t)b << 14) + ((size_t)t << 8) + f;
  float d = D[g];
  int fs = f ^ ((b & 7) << 3);
  int row = tl * 1024 + b;
  Dbfs[(size_t)row * 256 + fs] = (bf16)d;
  float gx = __expf(-fmaxf(d * w_gx[f] + b_gx[f], 0.f));
  float xh = gx * L[g] + (1.f - gx) * Mean[(size_t)b * 256 + f];
  float m  = Msk[g];
  float xr = m * X[g] + (1.f - m) * xh;
  if (tl < 16) {
    size_t xo = (size_t)row * 512;
    XRs[xo + fs]       = (bf16)xr;
    XRs[xo + 256 + fs] = (bf16)m;
  }
}

// ---------------------------------------------------------------------------
// wprep: tiled+swizzled weight images
// ---------------------------------------------------------------------------
__global__ void wprep_kernel(const float* __restrict__ w_ih, const float* __restrict__ w_hh,
                             const float* __restrict__ b_ih, const float* __restrict__ b_hh,
                             const float* __restrict__ w_gh,
                             bf16* __restrict__ WcH2, bf16* __restrict__ WcX2,
                             bf16* __restrict__ Wgs, float* __restrict__ bias4) {
  int i = blockIdx.x * 256 + threadIdx.x;
  if (i < 4194304) {                       // WcH2: [nb32][kt16][nl128][c8][e8]
    int blk = i >> 13;
    int nb = blk >> 4, kt = blk & 15;
    int r = i & 8191;
    int nl = r >> 6, cc = (r >> 3) & 7, e = r & 7;
    int n = ((nl >> 5) << 10) + nb * 32 + (nl & 31);
    int gg = n >> 10, j = n & 1023;
    int k = kt * 64 + ((cc ^ (nl & 7)) << 3) + e;   // h-part col 0..1023
    float v;
    if (gg == 3) v = w_hh[(size_t)(2048 + j) * 1024 + k];
    else {
      int rr = gg * 1024 + j;
      v = w_ih[(size_t)rr * 1536 + 256 + k];
      if (gg < 2) v += w_hh[(size_t)rr * 1024 + k];
    }
    WcH2[i] = (bf16)v;
  } else if (i < 6291456) {                // WcX2: [nb32][kt8][nl128][c8][e8]
    int q = i - 4194304;
    int blk = q >> 13;
    int nb = blk >> 3, kt = blk & 7;
    int r = q & 8191;
    int nl = r >> 6, cc = (r >> 3) & 7, e = r & 7;
    int n = ((nl >> 5) << 10) + nb * 32 + (nl & 31);
    int gg = n >> 10, j = n & 1023;
    int k = kt * 64 + ((cc ^ (nl & 7)) << 3) + e;   // x/m-part col 0..511
    float v = 0.f;
    if (gg < 3) {
      int rr = gg * 1024 + j;
      v = (k < 256) ? w_ih[(size_t)rr * 1536 + k]
                    : w_ih[(size_t)rr * 1536 + 1280 + (k - 256)];
    }
    WcX2[q] = (bf16)v;
  } else if (i < 6553600) {                // Wgs: [nb8][kt4][nl128][c8][e8]
    int q = i - 6291456;
    int blk = q >> 13;
    int nb = blk >> 2, kt = blk & 3;
    int r = q & 8191;
    int nl = r >> 6, cc = (r >> 3) & 7, e = r & 7;
    int n = nb * 128 + nl;
    int k = kt * 64 + ((cc ^ (nl & 7)) << 3) + e;
    Wgs[q] = (bf16)w_gh[(size_t)n * 256 + k];
  } else if (i < 6557696) {                // bias4
    int q = i - 6553600;
    int gg = q >> 10, j = q & 1023;
    float v;
    if (gg == 0)      v = b_ih[j] + b_hh[j];
    else if (gg == 1) v = b_ih[1024 + j] + b_hh[1024 + j];
    else if (gg == 2) v = b_ih[2048 + j];
    else              v = b_hh[2048 + j];
    bias4[q] = v;
  }
}

// ---------------------------------------------------------------------------
// gammah: GH = exp(-relu(Dbfs . Wg^T + b_gh)); 128x128 tile, gll16 2-phase
// ---------------------------------------------------------------------------
__global__ __launch_bounds__(256) void gammah_kernel(const bf16* __restrict__ Dbfs,
                                                     const bf16* __restrict__ Wgs,
                                                     const float* __restrict__ b_gh,
                                                     bf16* __restrict__ GH, int mbcnt) {
  __shared__ char As[2][16384];
  __shared__ char Bs[2][16384];
  int tid = threadIdx.x, lane = tid & 63, wid = tid >> 6;
  int wr = wid >> 1, wc = wid & 1;
  int cpx = gridDim.x >> 3;
  int wg = (blockIdx.x & 7) * cpx + (blockIdx.x >> 3);
  int mb = wg % mbcnt, nb = wg / mbcnt;

  const bf16* aA = Dbfs + ((size_t)(mb * 128 + wid * 8 + (lane >> 3))) * 256 + (lane & 7) * 8;
  const bf16* aB = Wgs + (size_t)nb * 4 * 8192 + wid * 512 + lane * 8;

  f32x4 acc[4][4];
#pragma unroll
  for (int a = 0; a < 4; ++a)
#pragma unroll
    for (int b = 0; b < 4; ++b)
#pragma unroll
      for (int q = 0; q < 4; ++q) acc[a][b][q] = 0.f;

#define GM_STAGE(buf, kt)                                                    \
  do {                                                                       \
    _Pragma("unroll")                                                        \
    for (int q = 0; q < 4; ++q)                                              \
      GLL16(aA + q * (32 * 256) + (kt) * 64, &As[buf][(q * 4 + wid) * 1024]); \
    _Pragma("unroll")                                                        \
    for (int q = 0; q < 4; ++q)                                              \
      GLL16(aB + (size_t)(kt) * 8192 + q * 2048, &Bs[buf][(q * 4 + wid) * 1024]); \
  } while (0)

  GM_STAGE(0, 0);
  __syncthreads();
  for (int kt = 0; kt < 4; ++kt) {
    const int cur = kt & 1;
    if (kt < 3) GM_STAGE(cur ^ 1, kt + 1);
#pragma unroll
    for (int kk = 0; kk < 2; ++kk) {
      int kb = kk * 64 + ((lane >> 4) << 4);
      bf16x8 af[4], bfr[4];
#pragma unroll
      for (int mf = 0; mf < 4; ++mf) {
        int row = wr * 64 + mf * 16 + (lane & 15);
        af[mf] = *(const bf16x8*)&As[cur][(row * 128 + kb) ^ ((row & 7) << 4)];
      }
#pragma unroll
      for (int nf = 0; nf < 4; ++nf) {
        int nl = wc * 64 + nf * 16 + (lane & 15);
        bfr[nf] = *(const bf16x8*)&Bs[cur][(nl * 128 + kb) ^ ((nl & 7) << 4)];
      }
#pragma unroll
      for (int mf = 0; mf < 4; ++mf)
#pragma unroll
        for (int nf = 0; nf < 4; ++nf)
          acc[mf][nf] = __builtin_amdgcn_mfma_f32_16x16x32_bf16(af[mf], bfr[nf], acc[mf][nf], 0, 0, 0);
    }
    __syncthreads();
  }
#pragma unroll
  for (int nf = 0; nf < 4; ++nf) {
    int n = nb * 128 + wc * 64 + nf * 16 + (lane & 15);
    float bg = b_gh[n];
#pragma unroll
    for (int mf = 0; mf < 4; ++mf)
#pragma unroll
      for (int reg = 0; reg < 4; ++reg) {
        int m = mb * 128 + wr * 64 + mf * 16 + ((lane >> 4) << 2) + reg;
        GH[(size_t)m * 1024 + n] = (bf16)__expf(-fmaxf(acc[mf][nf][reg] + bg, 0.f));
      }
  }
}

// ---------------------------------------------------------------------------
// gix: Gi = XRs . WcX^T (gate-interleaved N); 128x128 tile, gll16 2-phase
// ---------------------------------------------------------------------------
__global__ __launch_bounds__(256) void gix_kernel(const bf16* __restrict__ XRs,
                                                  const bf16* __restrict__ WcX2,
                                                  bf16* __restrict__ Gi, int mbshift) {
  __shared__ char As[2][16384];
  __shared__ char Bs[2][16384];
  int tid = threadIdx.x, lane = tid & 63, wid = tid >> 6;
  int wr = wid >> 1, wc = wid & 1;
  int cpx = gridDim.x >> 3;
  int wg = (blockIdx.x & 7) * cpx + (blockIdx.x >> 3);
  int mb = wg & ((1 << mbshift) - 1), nb = wg >> mbshift;

  const bf16* aA = XRs + ((size_t)(mb * 128 + wid * 8 + (lane >> 3))) * 512 + (lane & 7) * 8;
  const bf16* aB = WcX2 + (size_t)nb * 8 * 8192 + wid * 512 + lane * 8;

  f32x4 acc[4][4];
#pragma unroll
  for (int a = 0; a < 4; ++a)
#pragma unroll
    for (int b = 0; b < 4; ++b)
#pragma unroll
      for (int q = 0; q < 4; ++q) acc[a][b][q] = 0.f;

#define GX_STAGE(buf, kt)                                                    \
  do {                                                                       \
    _Pragma("unroll")                                                        \
    for (int q = 0; q < 4; ++q)                                              \
      GLL16(aA + q * (32 * 512) + (kt) * 64, &As[buf][(q * 4 + wid) * 1024]); \
    _Pragma("unroll")                                                        \
    for (int q = 0; q < 4; ++q)                                              \
      GLL16(aB + (size_t)(kt) * 8192 + q * 2048, &Bs[buf][(q * 4 + wid) * 1024]); \
  } while (0)

  GX_STAGE(0, 0);
  __syncthreads();
  for (int kt = 0; kt < 8; ++kt) {
    const int cur = kt & 1;
    if (kt < 7) GX_STAGE(cur ^ 1, kt + 1);
#pragma unroll
    for (int kk = 0; kk < 2; ++kk) {
      int kb = kk * 64 + ((lane >> 4) << 4);
      bf16x8 af[4], bfr[4];
#pragma unroll
      for (int mf = 0; mf < 4; ++mf) {
        int row = wr * 64 + mf * 16 + (lane & 15);
        af[mf] = *(const bf16x8*)&As[cur][(row * 128 + kb) ^ ((row & 7) << 4)];
      }
#pragma unroll
      for (int nf = 0; nf < 4; ++nf) {
        int nl = wc * 64 + nf * 16 + (lane & 15);
        bfr[nf] = *(const bf16x8*)&Bs[cur][(nl * 128 + kb) ^ ((nl & 7) << 4)];
      }
#pragma unroll
      for (int mf = 0; mf < 4; ++mf)
#pragma unroll
        for (int nf = 0; nf < 4; ++nf)
          acc[mf][nf] = __builtin_amdgcn_mfma_f32_16x16x32_bf16(af[mf], bfr[nf], acc[mf][nf], 0, 0, 0);
    }
    __syncthreads();
  }
#pragma unroll
  for (int nf = 0; nf < 4; ++nf) {
    int nl = wc * 64 + nf * 16 + (lane & 15);
    int n = ((nl >> 5) << 10) + nb * 32 + (nl & 31);
#pragma unroll
    for (int mf = 0; mf < 4; ++mf)
#pragma unroll
      for (int reg = 0; reg < 4; ++reg) {
        int m = mb * 128 + wr * 64 + mf * 16 + ((lane >> 4) << 2) + reg;
        Gi[(size_t)m * 4096 + n] = (bf16)acc[mf][nf][reg];
      }
  }
}

// ---------------------------------------------------------------------------
// step: h-part GEMM (64x128 tile, K=1024) + fused GRU epilogue + decay
// ---------------------------------------------------------------------------
__global__ __launch_bounds__(256) void step_kernel(
    const bf16* __restrict__ hbs, const float* __restrict__ hf,
    const bf16* __restrict__ WcH2, const float* __restrict__ bias4,
    const bf16* __restrict__ gi, const bf16* __restrict__ gh_next, int is_last,
    float* __restrict__ hf_next, bf16* __restrict__ hbs_next) {
  __shared__ char As[2][8192];
  __shared__ char Bs[2][16384];
  int tid = threadIdx.x, lane = tid & 63, wid = tid >> 6;
  int wr = wid >> 1, wc = wid & 1;
  int wg = ((blockIdx.x & 7) << 6) + (blockIdx.x >> 3);
  int mb = wg & 15, nb = wg >> 4;

  const bf16* aA = hbs + ((size_t)(mb * 64 + wid * 8 + (lane >> 3))) * 1024 + (lane & 7) * 8;
  const bf16* aB = WcH2 + (size_t)nb * 16 * 8192 + wid * 512 + lane * 8;

  f32x4 acc[2][4];
#pragma unroll
  for (int a = 0; a < 2; ++a)
#pragma unroll
    for (int b = 0; b < 4; ++b)
#pragma unroll
      for (int q = 0; q < 4; ++q) acc[a][b][q] = 0.f;

#define ST_STAGE(buf, kt)                                                    \
  do {                                                                       \
    GLL16(aA + (kt) * 64, &As[buf][wid * 1024]);                             \
    GLL16(aA + 32 * 1024 + (kt) * 64, &As[buf][(wid + 4) * 1024]);           \
    const bf16* bsrc = aB + (size_t)(kt) * 8192;                             \
    GLL16(bsrc,        &Bs[buf][wid * 1024]);                                \
    GLL16(bsrc + 2048, &Bs[buf][(wid + 4) * 1024]);                          \
    GLL16(bsrc + 4096, &Bs[buf][(wid + 8) * 1024]);                          \
    GLL16(bsrc + 6144, &Bs[buf][(wid + 12) * 1024]);                         \
  } while (0)

  ST_STAGE(0, 0);
  __syncthreads();
  for (int kt = 0; kt < 16; ++kt) {
    const int cur = kt & 1;
    if (kt < 15) ST_STAGE(cur ^ 1, kt + 1);
#pragma unroll
    for (int kk = 0; kk < 2; ++kk) {
      int kb = kk * 64 + ((lane >> 4) << 4);
      bf16x8 af[2], bfr[4];
#pragma unroll
      for (int mf = 0; mf < 2; ++mf) {
        int row = wr * 32 + mf * 16 + (lane & 15);
        af[mf] = *(const bf16x8*)&As[cur][(row * 128 + kb) ^ ((row & 7) << 4)];
      }
#pragma unroll
      for (int g = 0; g < 4; ++g) {
        int nl = g * 32 + wc * 16 + (lane & 15);
        bfr[g] = *(const bf16x8*)&Bs[cur][(nl * 128 + kb) ^ ((nl & 7) << 4)];
      }
#pragma unroll
      for (int mf = 0; mf < 2; ++mf)
#pragma unroll
        for (int g = 0; g < 4; ++g)
          acc[mf][g] = __builtin_amdgcn_mfma_f32_16x16x32_bf16(af[mf], bfr[g], acc[mf][g], 0, 0, 0);
    }
    __syncthreads();
  }

  int j = nb * 32 + wc * 16 + (lane & 15);
  float br = bias4[j], bz = bias4[1024 + j], bn = bias4[2048 + j], bh = bias4[3072 + j];
#pragma unroll
  for (int mf = 0; mf < 2; ++mf) {
#pragma unroll
    for (int reg = 0; reg < 4; ++reg) {
      int brow = mb * 64 + wr * 32 + mf * 16 + ((lane >> 4) << 2) + reg;
      size_t gb = (size_t)brow * 4096 + j;
      float pr  = acc[mf][0][reg] + (float)gi[gb] + br;
      float pz  = acc[mf][1][reg] + (float)gi[gb + 1024] + bz;
      float pin = acc[mf][2][reg] + (float)gi[gb + 2048] + bn;
      float phn = acc[mf][3][reg] + bh;              // Gi gate-3 columns are 0
      float r = sigm(pr), z = sigm(pz);
      float nn = tanh_fast(pin + r * phn);
      size_t hb_ = (size_t)brow * 1024 + j;
      float hold = hf[hb_];
      float hnew = (1.f - z) * nn + z * hold;
      float gam = is_last ? 1.f : (float)gh_next[hb_];
      float hd = hnew * gam;
      hf_next[hb_] = hd;
      hbs_next[(size_t)brow * 1024 + (j ^ ((brow & 7) << 3))] = (bf16)hd;
    }
  }
}

// ---------------------------------------------------------------------------
// classifier + softmax
// ---------------------------------------------------------------------------
__global__ void cls_kernel(const float* __restrict__ h, const float* __restrict__ w_cls,
                           const float* __restrict__ b_cls, float* __restrict__ out) {
  int wid = threadIdx.x >> 6, lane = threadIdx.x & 63;
  int b = blockIdx.x * 4 + wid;
  const float* hb = h + (size_t)b * 1024;
  float a0 = 0.f, a1 = 0.f;
#pragma unroll
  for (int e = 0; e < 16; ++e) {
    int i = e * 64 + lane;
    float hv = hb[i];
    a0 += hv * w_cls[i];
    a1 += hv * w_cls[1024 + i];
  }
  for (int off = 32; off; off >>= 1) {
    a0 += __shfl_down(a0, off);
    a1 += __shfl_down(a1, off);
  }
  if (lane == 0) {
    float l0 = a0 + b_cls[0], l1 = a1 + b_cls[1];
    float mx = fmaxf(l0, l1);
    float e0 = __expf(l0 - mx), e1 = __expf(l1 - mx);
    float s = e0 + e1;
    out[b * 2]     = e0 / s;
    out[b * 2 + 1] = e1 / s;
  }
}

// ---------------------------------------------------------------------------
extern "C" void kernel_launch(void* const* d_in, const int* in_sizes, int n_in,
                              void* d_out, int out_size, void* d_ws, size_t ws_size,
                              hipStream_t stream) {
  const float* X     = (const float*)d_in[0];
  const float* Msk   = (const float*)d_in[1];
  const float* D     = (const float*)d_in[2];
  const float* Mean  = (const float*)d_in[3];
  const float* L     = (const float*)d_in[4];
  const float* w_gh  = (const float*)d_in[5];
  const float* b_gh  = (const float*)d_in[6];
  const float* w_gx  = (const float*)d_in[7];
  const float* b_gx  = (const float*)d_in[8];
  const float* w_ih  = (const float*)d_in[9];
  const float* w_hh  = (const float*)d_in[10];
  const float* b_ih  = (const float*)d_in[11];
  const float* b_hh  = (const float*)d_in[12];
  const float* w_cls = (const float*)d_in[13];
  const float* b_cls = (const float*)d_in[14];

  char* w = (char*)d_ws;
  bf16*  XRs   = (bf16*)(w);
  bf16*  Dbfs  = (bf16*)(w + 16777216);
  bf16*  GH    = (bf16*)(w + 25690112);
  bf16*  WcX2  = (bf16*)(w + 61341696);
  bf16*  WcH2  = (bf16*)(w + 65536000);
  bf16*  Wgs   = (bf16*)(w + 73924608);
  float* bias4 = (float*)(w + 74448896);
  float* hf0   = (float*)(w + 74465280);
  float* hf1   = (float*)(w + 78659584);
  bf16*  hb0   = (bf16*)(w + 82853888);
  bf16*  hb1   = (bf16*)(w + 84951040);
  bf16*  Gi    = (bf16*)(w + 87048192);

  size_t base = 87048192;
  int GCH = 16;
  while (GCH > 1 && base + (size_t)GCH * 8388608ull > ws_size) GCH >>= 1;
  int mbshift = 3;
  while ((1 << (mbshift - 3)) < GCH) ++mbshift;   // mbcnt = GCH*8 = 1<<mbshift

  float* hfp[2] = {hf0, hf1};
  bf16*  hbp[2] = {hb0, hb1};

  hipMemsetAsync(hf0, 0, 4194304, stream);
  hipMemsetAsync(hb0, 0, 2097152, stream);
  wprep_kernel<<<25616, 256, 0, stream>>>(w_ih, w_hh, b_ih, b_hh, w_gh, WcH2, WcX2, Wgs, bias4);

  int t = 0;
  for (int c = 0; c < 4; ++c) {
    int nsl = (c < 3) ? 17 : 16;
    prep_kernel<<<nsl * 1024, 256, 0, stream>>>(X, Msk, D, Mean, L, w_gx, b_gx, XRs, Dbfs, c, nsl);
    gammah_kernel<<<nsl * 64, 256, 0, stream>>>(Dbfs, Wgs, b_gh, GH, nsl * 8);
    for (int sub = 0; sub < 16 / GCH; ++sub) {
      gix_kernel<<<GCH * 256, 256, 0, stream>>>(XRs + (size_t)sub * GCH * 524288, WcX2, Gi, mbshift);
      for (int tl2 = 0; tl2 < GCH; ++tl2, ++t) {
        int tl = sub * GCH + tl2;
        int cur = t & 1, nxt = cur ^ 1;
        step_kernel<<<512, 256, 0, stream>>>(
            hbp[cur], hfp[cur], WcH2, bias4,
            Gi + (size_t)tl2 * 4194304, GH + (size_t)(tl + 1) * 1048576,
            (t == 63) ? 1 : 0, hfp[nxt], hbp[nxt]);
      }
    }
  }
  cls_kernel<<<256, 256, 0, stream>>>(hfp[0], w_cls, b_cls, (float*)d_out);
}

// Round 3
// 1618.331 us; speedup vs baseline: 1.5299x; 1.2883x over previous
//
#include <hip/hip_runtime.h>

using bf16   = __bf16;
using bf16x4 = __bf16 __attribute__((ext_vector_type(4)));
using bf16x8 = __bf16 __attribute__((ext_vector_type(8)));
using f32x4  = float  __attribute__((ext_vector_type(4)));

// B=1024, T=64, F=256, H=1024, C=2
// ws layout (bytes):
//  XRs   @0          16,777,216   [16][1024 b][512 k]   pre-swizzled (b&7) bf16
//  Dbfs  @16777216    8,912,896   [17][1024][256]       pre-swizzled (b&7) bf16
//  GH    @25690112   35,651,584   [17][1024][1024]      plain bf16
//  WcX2  @61341696    4,194,304   [nb32][kt8][nl128][64] tiled bf16 (n = j*4+g)
//  WcH2  @65536000    8,388,608   [nb32][kt16][nl128][64] tiled bf16 (n = g*1024+j)
//  Wgs   @73924608      524,288   [nb8][kt4][nl128][64] tiled bf16
//  bias4 @74448896       16,384   [4][1024] f32
//  hf0/1 @74465280    8,388,608   f32 state x2
//  hb0/1 @82853888    4,194,304   bf16 state x2, pre-swizzled (b&3)<<3
//  Gi    @87048192    GCH*8,388,608  [GCH][1024][1024 j][4 g] bf16

__device__ __forceinline__ float sigm(float x) { return 1.f / (1.f + __expf(-x)); }
__device__ __forceinline__ float tanh_fast(float x) {
  float e = __expf(2.f * x);
  return 1.f - 2.f / (e + 1.f);
}

#define GLL16(gsrc, ldst)                                                              \
  __builtin_amdgcn_global_load_lds((const __attribute__((address_space(1))) void*)(gsrc), \
                                   (__attribute__((address_space(3))) void*)(ldst), 16, 0, 0)

// ---------------------------------------------------------------------------
// prep: pre-swizzled XRs ([xr|m], f XOR (b&7)<<3) and Dbfs
// ---------------------------------------------------------------------------
__global__ void prep_kernel(const float* __restrict__ X, const float* __restrict__ Msk,
                            const float* __restrict__ D, const float* __restrict__ Mean,
                            const float* __restrict__ L, const float* __restrict__ w_gx,
                            const float* __restrict__ b_gx,
                            bf16* __restrict__ XRs, bf16* __restrict__ Dbfs,
                            int c, int nsl) {
  int i = blockIdx.x * 256 + threadIdx.x;
  if (i >= (nsl << 18)) return;
  int f = i & 255, b = (i >> 8) & 1023, tl = i >> 18;
  int t = c * 16 + tl;
  size_t g = ((size_t)b << 14) + ((size_t)t << 8) + f;
  float d = D[g];
  int fs = f ^ ((b & 7) << 3);
  int row = tl * 1024 + b;
  Dbfs[(size_t)row * 256 + fs] = (bf16)d;
  float gx = __expf(-fmaxf(d * w_gx[f] + b_gx[f], 0.f));
  float xh = gx * L[g] + (1.f - gx) * Mean[(size_t)b * 256 + f];
  float m  = Msk[g];
  float xr = m * X[g] + (1.f - m) * xh;
  if (tl < 16) {
    size_t xo = (size_t)row * 512;
    XRs[xo + fs]       = (bf16)xr;
    XRs[xo + 256 + fs] = (bf16)m;
  }
}

// ---------------------------------------------------------------------------
// wprep
// ---------------------------------------------------------------------------
__global__ void wprep_kernel(const float* __restrict__ w_ih, const float* __restrict__ w_hh,
                             const float* __restrict__ b_ih, const float* __restrict__ b_hh,
                             const float* __restrict__ w_gh,
                             bf16* __restrict__ WcH2, bf16* __restrict__ WcX2,
                             bf16* __restrict__ Wgs, float* __restrict__ bias4) {
  int i = blockIdx.x * 256 + threadIdx.x;
  if (i < 4194304) {                       // WcH2: [nb32][kt16][nl128][c8][e8], n=g*1024+j
    int blk = i >> 13;
    int nb = blk >> 4, kt = blk & 15;
    int r = i & 8191;
    int nl = r >> 6, cc = (r >> 3) & 7, e = r & 7;
    int n = ((nl >> 5) << 10) + nb * 32 + (nl & 31);
    int gg = n >> 10, j = n & 1023;
    int k = kt * 64 + ((cc ^ (nl & 7)) << 3) + e;
    float v;
    if (gg == 3) v = w_hh[(size_t)(2048 + j) * 1024 + k];
    else {
      int rr = gg * 1024 + j;
      v = w_ih[(size_t)rr * 1536 + 256 + k];
      if (gg < 2) v += w_hh[(size_t)rr * 1024 + k];
    }
    WcH2[i] = (bf16)v;
  } else if (i < 6291456) {                // WcX2: [nb32][kt8][nl128][c8][e8], n=j*4+g
    int q = i - 4194304;
    int blk = q >> 13;
    int nb = blk >> 3, kt = blk & 7;
    int r = q & 8191;
    int nl = r >> 6, cc = (r >> 3) & 7, e = r & 7;
    int n = nb * 128 + nl;
    int gg = n & 3, j = n >> 2;
    int k = kt * 64 + ((cc ^ (nl & 7)) << 3) + e;
    float v = 0.f;
    if (gg < 3) {
      int rr = gg * 1024 + j;
      v = (k < 256) ? w_ih[(size_t)rr * 1536 + k]
                    : w_ih[(size_t)rr * 1536 + 1280 + (k - 256)];
    }
    WcX2[q] = (bf16)v;
  } else if (i < 6553600) {                // Wgs
    int q = i - 6291456;
    int blk = q >> 13;
    int nb = blk >> 2, kt = blk & 3;
    int r = q & 8191;
    int nl = r >> 6, cc = (r >> 3) & 7, e = r & 7;
    int n = nb * 128 + nl;
    int k = kt * 64 + ((cc ^ (nl & 7)) << 3) + e;
    Wgs[q] = (bf16)w_gh[(size_t)n * 256 + k];
  } else if (i < 6557696) {                // bias4
    int q = i - 6553600;
    int gg = q >> 10, j = q & 1023;
    float v;
    if (gg == 0)      v = b_ih[j] + b_hh[j];
    else if (gg == 1) v = b_ih[1024 + j] + b_hh[1024 + j];
    else if (gg == 2) v = b_ih[2048 + j];
    else              v = b_hh[2048 + j];
    bias4[q] = v;
  }
}

// ---------------------------------------------------------------------------
// gammah: GH = exp(-relu(Dbfs . Wg^T + b_gh)); LDS-restaged coalesced epilogue
// ---------------------------------------------------------------------------
__global__ __launch_bounds__(256) void gammah_kernel(const bf16* __restrict__ Dbfs,
                                                     const bf16* __restrict__ Wgs,
                                                     const float* __restrict__ b_gh,
                                                     bf16* __restrict__ GH, int mbcnt) {
  __shared__ char smem[65536];
  char* As = smem;            // [2][16384]
  char* Bs = smem + 32768;    // [2][16384]
  int tid = threadIdx.x, lane = tid & 63, wid = tid >> 6;
  int wr = wid >> 1, wc = wid & 1;
  int cpx = gridDim.x >> 3;
  int wg = (blockIdx.x & 7) * cpx + (blockIdx.x >> 3);
  int mb = wg % mbcnt, nb = wg / mbcnt;

  const bf16* aA = Dbfs + ((size_t)(mb * 128 + wid * 8 + (lane >> 3))) * 256 + (lane & 7) * 8;
  const bf16* aB = Wgs + (size_t)nb * 4 * 8192 + wid * 512 + lane * 8;

  f32x4 acc[4][4];
#pragma unroll
  for (int a = 0; a < 4; ++a)
#pragma unroll
    for (int b = 0; b < 4; ++b)
#pragma unroll
      for (int q = 0; q < 4; ++q) acc[a][b][q] = 0.f;

#define GM_STAGE(buf, kt)                                                         \
  do {                                                                            \
    _Pragma("unroll")                                                             \
    for (int q = 0; q < 4; ++q)                                                   \
      GLL16(aA + q * (32 * 256) + (kt) * 64, As + (buf) * 16384 + (q * 4 + wid) * 1024); \
    _Pragma("unroll")                                                             \
    for (int q = 0; q < 4; ++q)                                                   \
      GLL16(aB + (size_t)(kt) * 8192 + q * 2048, Bs + (buf) * 16384 + (q * 4 + wid) * 1024); \
  } while (0)

  GM_STAGE(0, 0);
  __syncthreads();
  for (int kt = 0; kt < 4; ++kt) {
    const int cur = kt & 1;
    if (kt < 3) GM_STAGE(cur ^ 1, kt + 1);
#pragma unroll
    for (int kk = 0; kk < 2; ++kk) {
      int kb = kk * 64 + ((lane >> 4) << 4);
      bf16x8 af[4], bfr[4];
#pragma unroll
      for (int mf = 0; mf < 4; ++mf) {
        int row = wr * 64 + mf * 16 + (lane & 15);
        af[mf] = *(const bf16x8*)(As + cur * 16384 + (((row * 128 + kb)) ^ ((row & 7) << 4)));
      }
#pragma unroll
      for (int nf = 0; nf < 4; ++nf) {
        int nl = wc * 64 + nf * 16 + (lane & 15);
        bfr[nf] = *(const bf16x8*)(Bs + cur * 16384 + (((nl * 128 + kb)) ^ ((nl & 7) << 4)));
      }
#pragma unroll
      for (int mf = 0; mf < 4; ++mf)
#pragma unroll
        for (int nf = 0; nf < 4; ++nf)
          acc[mf][nf] = __builtin_amdgcn_mfma_f32_16x16x32_bf16(af[mf], bfr[nf], acc[mf][nf], 0, 0, 0);
    }
    __syncthreads();
  }
  // epilogue: activation -> LDS (chunk-XOR) -> coalesced 16B stores
  char* ep = smem;   // 128 rows x 256B
#pragma unroll
  for (int nf = 0; nf < 4; ++nf) {
    int col = wc * 64 + nf * 16 + (lane & 15);
    float bg = b_gh[nb * 128 + col];
#pragma unroll
    for (int mf = 0; mf < 4; ++mf)
#pragma unroll
      for (int reg = 0; reg < 4; ++reg) {
        int row = wr * 64 + mf * 16 + ((lane >> 4) << 2) + reg;
        int cph = ((col >> 3) ^ (((row >> 2) & 3) << 2));
        *(bf16*)(ep + row * 256 + (cph << 4) + (col & 7) * 2) =
            (bf16)__expf(-fmaxf(acc[mf][nf][reg] + bg, 0.f));
      }
  }
  __syncthreads();
#pragma unroll
  for (int p = 0; p < 8; ++p) {
    int idx = p * 256 + tid;
    int row = idx >> 4, c = idx & 15;
    int cph = c ^ (((row >> 2) & 3) << 2);
    bf16x8 v = *(const bf16x8*)(ep + row * 256 + (cph << 4));
    *(bf16x8*)(GH + (size_t)(mb * 128 + row) * 1024 + nb * 128 + c * 8) = v;
  }
}

// ---------------------------------------------------------------------------
// gix: Gi[m][j*4+g] = XRs . WcX^T; LDS-restaged coalesced epilogue
// ---------------------------------------------------------------------------
__global__ __launch_bounds__(256) void gix_kernel(const bf16* __restrict__ XRs,
                                                  const bf16* __restrict__ WcX2,
                                                  bf16* __restrict__ Gi, int mbshift) {
  __shared__ char smem[65536];
  char* As = smem;
  char* Bs = smem + 32768;
  int tid = threadIdx.x, lane = tid & 63, wid = tid >> 6;
  int wr = wid >> 1, wc = wid & 1;
  int cpx = gridDim.x >> 3;
  int wg = (blockIdx.x & 7) * cpx + (blockIdx.x >> 3);
  int mb = wg & ((1 << mbshift) - 1), nb = wg >> mbshift;

  const bf16* aA = XRs + ((size_t)(mb * 128 + wid * 8 + (lane >> 3))) * 512 + (lane & 7) * 8;
  const bf16* aB = WcX2 + (size_t)nb * 8 * 8192 + wid * 512 + lane * 8;

  f32x4 acc[4][4];
#pragma unroll
  for (int a = 0; a < 4; ++a)
#pragma unroll
    for (int b = 0; b < 4; ++b)
#pragma unroll
      for (int q = 0; q < 4; ++q) acc[a][b][q] = 0.f;

#define GX_STAGE(buf, kt)                                                         \
  do {                                                                            \
    _Pragma("unroll")                                                             \
    for (int q = 0; q < 4; ++q)                                                   \
      GLL16(aA + q * (32 * 512) + (kt) * 64, As + (buf) * 16384 + (q * 4 + wid) * 1024); \
    _Pragma("unroll")                                                             \
    for (int q = 0; q < 4; ++q)                                                   \
      GLL16(aB + (size_t)(kt) * 8192 + q * 2048, Bs + (buf) * 16384 + (q * 4 + wid) * 1024); \
  } while (0)

  GX_STAGE(0, 0);
  __syncthreads();
  for (int kt = 0; kt < 8; ++kt) {
    const int cur = kt & 1;
    if (kt < 7) GX_STAGE(cur ^ 1, kt + 1);
#pragma unroll
    for (int kk = 0; kk < 2; ++kk) {
      int kb = kk * 64 + ((lane >> 4) << 4);
      bf16x8 af[4], bfr[4];
#pragma unroll
      for (int mf = 0; mf < 4; ++mf) {
        int row = wr * 64 + mf * 16 + (lane & 15);
        af[mf] = *(const bf16x8*)(As + cur * 16384 + (((row * 128 + kb)) ^ ((row & 7) << 4)));
      }
#pragma unroll
      for (int nf = 0; nf < 4; ++nf) {
        int nl = wc * 64 + nf * 16 + (lane & 15);
        bfr[nf] = *(const bf16x8*)(Bs + cur * 16384 + (((nl * 128 + kb)) ^ ((nl & 7) << 4)));
      }
#pragma unroll
      for (int mf = 0; mf < 4; ++mf)
#pragma unroll
        for (int nf = 0; nf < 4; ++nf)
          acc[mf][nf] = __builtin_amdgcn_mfma_f32_16x16x32_bf16(af[mf], bfr[nf], acc[mf][nf], 0, 0, 0);
    }
    __syncthreads();
  }
  char* ep = smem;
#pragma unroll
  for (int nf = 0; nf < 4; ++nf) {
    int col = wc * 64 + nf * 16 + (lane & 15);
#pragma unroll
    for (int mf = 0; mf < 4; ++mf)
#pragma unroll
      for (int reg = 0; reg < 4; ++reg) {
        int row = wr * 64 + mf * 16 + ((lane >> 4) << 2) + reg;
        int cph = ((col >> 3) ^ (((row >> 2) & 3) << 2));
        *(bf16*)(ep + row * 256 + (cph << 4) + (col & 7) * 2) = (bf16)acc[mf][nf][reg];
      }
  }
  __syncthreads();
#pragma unroll
  for (int p = 0; p < 8; ++p) {
    int idx = p * 256 + tid;
    int row = idx >> 4, c = idx & 15;
    int cph = c ^ (((row >> 2) & 3) << 2);
    bf16x8 v = *(const bf16x8*)(ep + row * 256 + (cph << 4));
    *(bf16x8*)(Gi + (size_t)(mb * 128 + row) * 4096 + nb * 128 + c * 8) = v;
  }
}

// ---------------------------------------------------------------------------
// step: h-part GEMM (64x128 tile, K=1024) + fused GRU epilogue + decay
// state swizzle: 4-row period ((b&3)<<3 elems)
// ---------------------------------------------------------------------------
__global__ __launch_bounds__(256) void step_kernel(
    const bf16* __restrict__ hbs, const float* __restrict__ hf,
    const bf16* __restrict__ WcH2, const float* __restrict__ bias4,
    const bf16* __restrict__ gi, const bf16* __restrict__ gh_next, int is_last,
    float* __restrict__ hf_next, bf16* __restrict__ hbs_next) {
  __shared__ char smem[49152];
  char* As = smem;            // [2][8192]
  char* Bs = smem + 16384;    // [2][16384]
  int tid = threadIdx.x, lane = tid & 63, wid = tid >> 6;
  int wr = wid >> 1, wc = wid & 1;
  int wg = ((blockIdx.x & 7) << 6) + (blockIdx.x >> 3);
  int mb = wg & 15, nb = wg >> 4;

  const bf16* aA = hbs + ((size_t)(mb * 64 + wid * 8 + (lane >> 3))) * 1024 + (lane & 7) * 8;
  const bf16* aB = WcH2 + (size_t)nb * 16 * 8192 + wid * 512 + lane * 8;

  // ---- epilogue prefetch: gi (3 gates packed), gh_next, hf ----
  int j = nb * 32 + wc * 16 + (lane & 15);
  bf16x4 giv[2][4];
  bf16   ghv[2][4];
  float  hfv[2][4];
#pragma unroll
  for (int mf = 0; mf < 2; ++mf)
#pragma unroll
    for (int reg = 0; reg < 4; ++reg) {
      int brow = mb * 64 + wr * 32 + mf * 16 + ((lane >> 4) << 2) + reg;
      size_t hb_ = (size_t)brow * 1024 + j;
      giv[mf][reg] = *(const bf16x4*)(gi + ((size_t)brow << 12) + (j << 2));
      ghv[mf][reg] = gh_next[hb_];
      hfv[mf][reg] = hf[hb_];
    }

  f32x4 acc[2][4];
#pragma unroll
  for (int a = 0; a < 2; ++a)
#pragma unroll
    for (int b = 0; b < 4; ++b)
#pragma unroll
      for (int q = 0; q < 4; ++q) acc[a][b][q] = 0.f;

#define ST_STAGE(buf, kt)                                                    \
  do {                                                                       \
    GLL16(aA + (kt) * 64, As + (buf) * 8192 + wid * 1024);                   \
    GLL16(aA + 32 * 1024 + (kt) * 64, As + (buf) * 8192 + (wid + 4) * 1024); \
    const bf16* bsrc = aB + (size_t)(kt) * 8192;                             \
    GLL16(bsrc,        Bs + (buf) * 16384 + wid * 1024);                     \
    GLL16(bsrc + 2048, Bs + (buf) * 16384 + (wid + 4) * 1024);               \
    GLL16(bsrc + 4096, Bs + (buf) * 16384 + (wid + 8) * 1024);               \
    GLL16(bsrc + 6144, Bs + (buf) * 16384 + (wid + 12) * 1024);              \
  } while (0)

  ST_STAGE(0, 0);
  __syncthreads();
  for (int kt = 0; kt < 16; ++kt) {
    const int cur = kt & 1;
    if (kt < 15) ST_STAGE(cur ^ 1, kt + 1);
#pragma unroll
    for (int kk = 0; kk < 2; ++kk) {
      int kb = kk * 64 + ((lane >> 4) << 4);
      bf16x8 af[2], bfr[4];
#pragma unroll
      for (int mf = 0; mf < 2; ++mf) {
        int row = wr * 32 + mf * 16 + (lane & 15);
        af[mf] = *(const bf16x8*)(As + cur * 8192 + (((row * 128 + kb)) ^ ((row & 3) << 4)));
      }
#pragma unroll
      for (int g = 0; g < 4; ++g) {
        int nl = g * 32 + wc * 16 + (lane & 15);
        bfr[g] = *(const bf16x8*)(Bs + cur * 16384 + (((nl * 128 + kb)) ^ ((nl & 7) << 4)));
      }
#pragma unroll
      for (int mf = 0; mf < 2; ++mf)
#pragma unroll
        for (int g = 0; g < 4; ++g)
          acc[mf][g] = __builtin_amdgcn_mfma_f32_16x16x32_bf16(af[mf], bfr[g], acc[mf][g], 0, 0, 0);
    }
    __syncthreads();
  }

  // fused GRU epilogue
  char* ep2 = smem;   // 64 rows x 64B, chunk-XOR
  float br = bias4[j], bz = bias4[1024 + j], bn = bias4[2048 + j], bh = bias4[3072 + j];
  int jc = wc * 16 + (lane & 15);
#pragma unroll
  for (int mf = 0; mf < 2; ++mf) {
#pragma unroll
    for (int reg = 0; reg < 4; ++reg) {
      int lr = wr * 32 + mf * 16 + ((lane >> 4) << 2) + reg;
      int brow = mb * 64 + lr;
      float pr  = acc[mf][0][reg] + (float)giv[mf][reg][0] + br;
      float pz  = acc[mf][1][reg] + (float)giv[mf][reg][1] + bz;
      float pin = acc[mf][2][reg] + (float)giv[mf][reg][2] + bn;
      float phn = acc[mf][3][reg] + bh;
      float r = sigm(pr), z = sigm(pz);
      float nn = tanh_fast(pin + r * phn);
      float hnew = (1.f - z) * nn + z * hfv[mf][reg];
      float gam = is_last ? 1.f : (float)ghv[mf][reg];
      float hd = hnew * gam;
      hf_next[(size_t)brow * 1024 + j] = hd;
      int cph = (jc >> 3) ^ ((lr >> 2) & 3);
      *(bf16*)(ep2 + lr * 64 + (cph << 4) + (jc & 7) * 2) = (bf16)hd;
    }
  }
  __syncthreads();
  {
    int lr = tid >> 2, c = tid & 3;
    int cph = c ^ ((lr >> 2) & 3);
    bf16x8 v = *(const bf16x8*)(ep2 + lr * 64 + (cph << 4));
    int brow = mb * 64 + lr;
    int el = (nb * 32 + c * 8) ^ ((brow & 3) << 3);
    *(bf16x8*)(hbs_next + (size_t)brow * 1024 + el) = v;
  }
}

// ---------------------------------------------------------------------------
// classifier + softmax
// ---------------------------------------------------------------------------
__global__ void cls_kernel(const float* __restrict__ h, const float* __restrict__ w_cls,
                           const float* __restrict__ b_cls, float* __restrict__ out) {
  int wid = threadIdx.x >> 6, lane = threadIdx.x & 63;
  int b = blockIdx.x * 4 + wid;
  const float* hb = h + (size_t)b * 1024;
  float a0 = 0.f, a1 = 0.f;
#pragma unroll
  for (int e = 0; e < 16; ++e) {
    int i = e * 64 + lane;
    float hv = hb[i];
    a0 += hv * w_cls[i];
    a1 += hv * w_cls[1024 + i];
  }
  for (int off = 32; off; off >>= 1) {
    a0 += __shfl_down(a0, off);
    a1 += __shfl_down(a1, off);
  }
  if (lane == 0) {
    float l0 = a0 + b_cls[0], l1 = a1 + b_cls[1];
    float mx = fmaxf(l0, l1);
    float e0 = __expf(l0 - mx), e1 = __expf(l1 - mx);
    float s = e0 + e1;
    out[b * 2]     = e0 / s;
    out[b * 2 + 1] = e1 / s;
  }
}

// ---------------------------------------------------------------------------
extern "C" void kernel_launch(void* const* d_in, const int* in_sizes, int n_in,
                              void* d_out, int out_size, void* d_ws, size_t ws_size,
                              hipStream_t stream) {
  const float* X     = (const float*)d_in[0];
  const float* Msk   = (const float*)d_in[1];
  const float* D     = (const float*)d_in[2];
  const float* Mean  = (const float*)d_in[3];
  const float* L     = (const float*)d_in[4];
  const float* w_gh  = (const float*)d_in[5];
  const float* b_gh  = (const float*)d_in[6];
  const float* w_gx  = (const float*)d_in[7];
  const float* b_gx  = (const float*)d_in[8];
  const float* w_ih  = (const float*)d_in[9];
  const float* w_hh  = (const float*)d_in[10];
  const float* b_ih  = (const float*)d_in[11];
  const float* b_hh  = (const float*)d_in[12];
  const float* w_cls = (const float*)d_in[13];
  const float* b_cls = (const float*)d_in[14];

  char* w = (char*)d_ws;
  bf16*  XRs   = (bf16*)(w);
  bf16*  Dbfs  = (bf16*)(w + 16777216);
  bf16*  GH    = (bf16*)(w + 25690112);
  bf16*  WcX2  = (bf16*)(w + 61341696);
  bf16*  WcH2  = (bf16*)(w + 65536000);
  bf16*  Wgs   = (bf16*)(w + 73924608);
  float* bias4 = (float*)(w + 74448896);
  float* hf0   = (float*)(w + 74465280);
  float* hf1   = (float*)(w + 78659584);
  bf16*  hb0   = (bf16*)(w + 82853888);
  bf16*  hb1   = (bf16*)(w + 84951040);
  bf16*  Gi    = (bf16*)(w + 87048192);

  size_t base = 87048192;
  int GCH = 16;
  while (GCH > 1 && base + (size_t)GCH * 8388608ull > ws_size) GCH >>= 1;
  int mbshift = 3;
  while ((1 << (mbshift - 3)) < GCH) ++mbshift;   // mbcnt = GCH*8

  float* hfp[2] = {hf0, hf1};
  bf16*  hbp[2] = {hb0, hb1};

  hipMemsetAsync(hf0, 0, 4194304, stream);
  hipMemsetAsync(hb0, 0, 2097152, stream);
  wprep_kernel<<<25616, 256, 0, stream>>>(w_ih, w_hh, b_ih, b_hh, w_gh, WcH2, WcX2, Wgs, bias4);

  int t = 0;
  for (int c = 0; c < 4; ++c) {
    int nsl = (c < 3) ? 17 : 16;
    prep_kernel<<<nsl * 1024, 256, 0, stream>>>(X, Msk, D, Mean, L, w_gx, b_gx, XRs, Dbfs, c, nsl);
    gammah_kernel<<<nsl * 64, 256, 0, stream>>>(Dbfs, Wgs, b_gh, GH, nsl * 8);
    for (int sub = 0; sub < 16 / GCH; ++sub) {
      gix_kernel<<<GCH * 256, 256, 0, stream>>>(XRs + (size_t)sub * GCH * 524288, WcX2, Gi, mbshift);
      for (int tl2 = 0; tl2 < GCH; ++tl2, ++t) {
        int tl = sub * GCH + tl2;
        int cur = t & 1, nxt = cur ^ 1;
        step_kernel<<<512, 256, 0, stream>>>(
            hbp[cur], hfp[cur], WcH2, bias4,
            Gi + (size_t)tl2 * 4194304, GH + (size_t)(tl + 1) * 1048576,
            (t == 63) ? 1 : 0, hfp[nxt], hbp[nxt]);
      }
    }
  }
  cls_kernel<<<256, 256, 0, stream>>>(hfp[0], w_cls, b_cls, (float*)d_out);
}

// Round 4
// 1565.601 us; speedup vs baseline: 1.5814x; 1.0337x over previous
//
#include <hip/hip_runtime.h>

using bf16   = __bf16;
using bf16x4 = __bf16 __attribute__((ext_vector_type(4)));
using bf16x8 = __bf16 __attribute__((ext_vector_type(8)));
using f32x4  = float  __attribute__((ext_vector_type(4)));

// B=1024, T=64, F=256, H=1024, C=2
// ws layout (bytes):
//  XRs   @0          16,777,216   [16][1024 b][512 k]   pre-swizzled (b&7) bf16
//  Dbfs  @16777216    8,912,896   [17][1024][256]       pre-swizzled (b&7) bf16
//  GH    @25690112   35,651,584   [17][1024][1024]      plain bf16
//  WcX2  @61341696    4,194,304   [nb32][kt8][nl128][64] tiled bf16 (n = j*4+g)
//  WcH3  @65536000    8,388,608   [nb64][kt16][nl64][64] tiled bf16 (nl = g*16+jj)
//  Wgs   @73924608      524,288   [nb8][kt4][nl128][64] tiled bf16
//  bias4 @74448896       16,384   [4][1024] f32
//  hf0/1 @74465280    8,388,608   f32 state x2
//  hb0/1 @82853888    4,194,304   bf16 state x2, pre-swizzled (b&7)<<3
//  Gi    @87048192    GCH*8,388,608  [GCH][1024][1024 j][4 g] bf16

__device__ __forceinline__ float sigm(float x) { return 1.f / (1.f + __expf(-x)); }
__device__ __forceinline__ float tanh_fast(float x) {
  float e = __expf(2.f * x);
  return 1.f - 2.f / (e + 1.f);
}

#define GLL16(gsrc, ldst)                                                              \
  __builtin_amdgcn_global_load_lds((const __attribute__((address_space(1))) void*)(gsrc), \
                                   (__attribute__((address_space(3))) void*)(ldst), 16, 0, 0)

// ---------------------------------------------------------------------------
// prep: pre-swizzled XRs ([xr|m], f XOR (b&7)<<3) and Dbfs
// ---------------------------------------------------------------------------
__global__ void prep_kernel(const float* __restrict__ X, const float* __restrict__ Msk,
                            const float* __restrict__ D, const float* __restrict__ Mean,
                            const float* __restrict__ L, const float* __restrict__ w_gx,
                            const float* __restrict__ b_gx,
                            bf16* __restrict__ XRs, bf16* __restrict__ Dbfs,
                            int c, int nsl) {
  int i = blockIdx.x * 256 + threadIdx.x;
  if (i >= (nsl << 18)) return;
  int f = i & 255, b = (i >> 8) & 1023, tl = i >> 18;
  int t = c * 16 + tl;
  size_t g = ((size_t)b << 14) + ((size_t)t << 8) + f;
  float d = D[g];
  int fs = f ^ ((b & 7) << 3);
  int row = tl * 1024 + b;
  Dbfs[(size_t)row * 256 + fs] = (bf16)d;
  float gx = __expf(-fmaxf(d * w_gx[f] + b_gx[f], 0.f));
  float xh = gx * L[g] + (1.f - gx) * Mean[(size_t)b * 256 + f];
  float m  = Msk[g];
  float xr = m * X[g] + (1.f - m) * xh;
  if (tl < 16) {
    size_t xo = (size_t)row * 512;
    XRs[xo + fs]       = (bf16)xr;
    XRs[xo + 256 + fs] = (bf16)m;
  }
}

// ---------------------------------------------------------------------------
// wprep
// ---------------------------------------------------------------------------
__global__ void wprep_kernel(const float* __restrict__ w_ih, const float* __restrict__ w_hh,
                             const float* __restrict__ b_ih, const float* __restrict__ b_hh,
                             const float* __restrict__ w_gh,
                             bf16* __restrict__ WcH3, bf16* __restrict__ WcX2,
                             bf16* __restrict__ Wgs, float* __restrict__ bias4) {
  int i = blockIdx.x * 256 + threadIdx.x;
  if (i < 4194304) {                       // WcH3: [nb64][kt16][nl64][c8][e8], nl=g*16+jj
    int blk = i >> 12;
    int nb = blk >> 4, kt = blk & 15;
    int r = i & 4095;
    int nl = r >> 6, cc = (r >> 3) & 7, e = r & 7;
    int gg = nl >> 4, j = nb * 16 + (nl & 15);
    int k = kt * 64 + ((cc ^ (nl & 7)) << 3) + e;
    float v;
    if (gg == 3) v = w_hh[(size_t)(2048 + j) * 1024 + k];
    else {
      int rr = gg * 1024 + j;
      v = w_ih[(size_t)rr * 1536 + 256 + k];
      if (gg < 2) v += w_hh[(size_t)rr * 1024 + k];
    }
    WcH3[i] = (bf16)v;
  } else if (i < 6291456) {                // WcX2: [nb32][kt8][nl128][c8][e8], n=j*4+g
    int q = i - 4194304;
    int blk = q >> 13;
    int nb = blk >> 3, kt = blk & 7;
    int r = q & 8191;
    int nl = r >> 6, cc = (r >> 3) & 7, e = r & 7;
    int n = nb * 128 + nl;
    int gg = n & 3, j = n >> 2;
    int k = kt * 64 + ((cc ^ (nl & 7)) << 3) + e;
    float v = 0.f;
    if (gg < 3) {
      int rr = gg * 1024 + j;
      v = (k < 256) ? w_ih[(size_t)rr * 1536 + k]
                    : w_ih[(size_t)rr * 1536 + 1280 + (k - 256)];
    }
    WcX2[q] = (bf16)v;
  } else if (i < 6553600) {                // Wgs
    int q = i - 6291456;
    int blk = q >> 13;
    int nb = blk >> 2, kt = blk & 3;
    int r = q & 8191;
    int nl = r >> 6, cc = (r >> 3) & 7, e = r & 7;
    int n = nb * 128 + nl;
    int k = kt * 64 + ((cc ^ (nl & 7)) << 3) + e;
    Wgs[q] = (bf16)w_gh[(size_t)n * 256 + k];
  } else if (i < 6557696) {                // bias4
    int q = i - 6553600;
    int gg = q >> 10, j = q & 1023;
    float v;
    if (gg == 0)      v = b_ih[j] + b_hh[j];
    else if (gg == 1) v = b_ih[1024 + j] + b_hh[1024 + j];
    else if (gg == 2) v = b_ih[2048 + j];
    else              v = b_hh[2048 + j];
    bias4[q] = v;
  }
}

// ---------------------------------------------------------------------------
// gammah: GH = exp(-relu(Dbfs . Wg^T + b_gh)); nb-fastest XCD sweep
// ---------------------------------------------------------------------------
__global__ __launch_bounds__(256) void gammah_kernel(const bf16* __restrict__ Dbfs,
                                                     const bf16* __restrict__ Wgs,
                                                     const float* __restrict__ b_gh,
                                                     bf16* __restrict__ GH) {
  __shared__ char smem[65536];
  char* As = smem;            // [2][16384]
  char* Bs = smem + 32768;    // [2][16384]
  int tid = threadIdx.x, lane = tid & 63, wid = tid >> 6;
  int wr = wid >> 1, wc = wid & 1;
  int cpx = gridDim.x >> 3;
  int wg = (blockIdx.x & 7) * cpx + (blockIdx.x >> 3);
  int nb = wg & 7, mb = wg >> 3;     // nb fastest: A-tile reused across 8 nb

  const bf16* aA = Dbfs + ((size_t)(mb * 128 + wid * 8 + (lane >> 3))) * 256 + (lane & 7) * 8;
  const bf16* aB = Wgs + (size_t)nb * 4 * 8192 + wid * 512 + lane * 8;

  f32x4 acc[4][4];
#pragma unroll
  for (int a = 0; a < 4; ++a)
#pragma unroll
    for (int b = 0; b < 4; ++b)
#pragma unroll
      for (int q = 0; q < 4; ++q) acc[a][b][q] = 0.f;

#define GM_STAGE(buf, kt)                                                         \
  do {                                                                            \
    _Pragma("unroll")                                                             \
    for (int q = 0; q < 4; ++q)                                                   \
      GLL16(aA + q * (32 * 256) + (kt) * 64, As + (buf) * 16384 + (q * 4 + wid) * 1024); \
    _Pragma("unroll")                                                             \
    for (int q = 0; q < 4; ++q)                                                   \
      GLL16(aB + (size_t)(kt) * 8192 + q * 2048, Bs + (buf) * 16384 + (q * 4 + wid) * 1024); \
  } while (0)

  GM_STAGE(0, 0);
  __syncthreads();
  for (int kt = 0; kt < 4; ++kt) {
    const int cur = kt & 1;
    if (kt < 3) GM_STAGE(cur ^ 1, kt + 1);
#pragma unroll
    for (int kk = 0; kk < 2; ++kk) {
      int kb = kk * 64 + ((lane >> 4) << 4);
      bf16x8 af[4], bfr[4];
#pragma unroll
      for (int mf = 0; mf < 4; ++mf) {
        int row = wr * 64 + mf * 16 + (lane & 15);
        af[mf] = *(const bf16x8*)(As + cur * 16384 + (((row * 128 + kb)) ^ ((row & 7) << 4)));
      }
#pragma unroll
      for (int nf = 0; nf < 4; ++nf) {
        int nl = wc * 64 + nf * 16 + (lane & 15);
        bfr[nf] = *(const bf16x8*)(Bs + cur * 16384 + (((nl * 128 + kb)) ^ ((nl & 7) << 4)));
      }
#pragma unroll
      for (int mf = 0; mf < 4; ++mf)
#pragma unroll
        for (int nf = 0; nf < 4; ++nf)
          acc[mf][nf] = __builtin_amdgcn_mfma_f32_16x16x32_bf16(af[mf], bfr[nf], acc[mf][nf], 0, 0, 0);
    }
    __syncthreads();
  }
  char* ep = smem;   // 128 rows x 256B
#pragma unroll
  for (int nf = 0; nf < 4; ++nf) {
    int col = wc * 64 + nf * 16 + (lane & 15);
    float bg = b_gh[nb * 128 + col];
#pragma unroll
    for (int mf = 0; mf < 4; ++mf)
#pragma unroll
      for (int reg = 0; reg < 4; ++reg) {
        int row = wr * 64 + mf * 16 + ((lane >> 4) << 2) + reg;
        int cph = ((col >> 3) ^ (((row >> 2) & 3) << 2));
        *(bf16*)(ep + row * 256 + (cph << 4) + (col & 7) * 2) =
            (bf16)__expf(-fmaxf(acc[mf][nf][reg] + bg, 0.f));
      }
  }
  __syncthreads();
#pragma unroll
  for (int p = 0; p < 8; ++p) {
    int idx = p * 256 + tid;
    int row = idx >> 4, c = idx & 15;
    int cph = c ^ (((row >> 2) & 3) << 2);
    bf16x8 v = *(const bf16x8*)(ep + row * 256 + (cph << 4));
    *(bf16x8*)(GH + (size_t)(mb * 128 + row) * 1024 + nb * 128 + c * 8) = v;
  }
}

// ---------------------------------------------------------------------------
// gix: Gi[m][j*4+g] = XRs . WcX^T; nb-fastest XCD sweep
// ---------------------------------------------------------------------------
__global__ __launch_bounds__(256) void gix_kernel(const bf16* __restrict__ XRs,
                                                  const bf16* __restrict__ WcX2,
                                                  bf16* __restrict__ Gi) {
  __shared__ char smem[65536];
  char* As = smem;
  char* Bs = smem + 32768;
  int tid = threadIdx.x, lane = tid & 63, wid = tid >> 6;
  int wr = wid >> 1, wc = wid & 1;
  int cpx = gridDim.x >> 3;
  int wg = (blockIdx.x & 7) * cpx + (blockIdx.x >> 3);
  int nb = wg & 31, mb = wg >> 5;    // nb fastest: A-tile (128KB) reused across 32 nb

  const bf16* aA = XRs + ((size_t)(mb * 128 + wid * 8 + (lane >> 3))) * 512 + (lane & 7) * 8;
  const bf16* aB = WcX2 + (size_t)nb * 8 * 8192 + wid * 512 + lane * 8;

  f32x4 acc[4][4];
#pragma unroll
  for (int a = 0; a < 4; ++a)
#pragma unroll
    for (int b = 0; b < 4; ++b)
#pragma unroll
      for (int q = 0; q < 4; ++q) acc[a][b][q] = 0.f;

#define GX_STAGE(buf, kt)                                                         \
  do {                                                                            \
    _Pragma("unroll")                                                             \
    for (int q = 0; q < 4; ++q)                                                   \
      GLL16(aA + q * (32 * 512) + (kt) * 64, As + (buf) * 16384 + (q * 4 + wid) * 1024); \
    _Pragma("unroll")                                                             \
    for (int q = 0; q < 4; ++q)                                                   \
      GLL16(aB + (size_t)(kt) * 8192 + q * 2048, Bs + (buf) * 16384 + (q * 4 + wid) * 1024); \
  } while (0)

  GX_STAGE(0, 0);
  __syncthreads();
  for (int kt = 0; kt < 8; ++kt) {
    const int cur = kt & 1;
    if (kt < 7) GX_STAGE(cur ^ 1, kt + 1);
#pragma unroll
    for (int kk = 0; kk < 2; ++kk) {
      int kb = kk * 64 + ((lane >> 4) << 4);
      bf16x8 af[4], bfr[4];
#pragma unroll
      for (int mf = 0; mf < 4; ++mf) {
        int row = wr * 64 + mf * 16 + (lane & 15);
        af[mf] = *(const bf16x8*)(As + cur * 16384 + (((row * 128 + kb)) ^ ((row & 7) << 4)));
      }
#pragma unroll
      for (int nf = 0; nf < 4; ++nf) {
        int nl = wc * 64 + nf * 16 + (lane & 15);
        bfr[nf] = *(const bf16x8*)(Bs + cur * 16384 + (((nl * 128 + kb)) ^ ((nl & 7) << 4)));
      }
#pragma unroll
      for (int mf = 0; mf < 4; ++mf)
#pragma unroll
        for (int nf = 0; nf < 4; ++nf)
          acc[mf][nf] = __builtin_amdgcn_mfma_f32_16x16x32_bf16(af[mf], bfr[nf], acc[mf][nf], 0, 0, 0);
    }
    __syncthreads();
  }
  char* ep = smem;
#pragma unroll
  for (int nf = 0; nf < 4; ++nf) {
    int col = wc * 64 + nf * 16 + (lane & 15);
#pragma unroll
    for (int mf = 0; mf < 4; ++mf)
#pragma unroll
      for (int reg = 0; reg < 4; ++reg) {
        int row = wr * 64 + mf * 16 + ((lane >> 4) << 2) + reg;
        int cph = ((col >> 3) ^ (((row >> 2) & 3) << 2));
        *(bf16*)(ep + row * 256 + (cph << 4) + (col & 7) * 2) = (bf16)acc[mf][nf][reg];
      }
  }
  __syncthreads();
#pragma unroll
  for (int p = 0; p < 8; ++p) {
    int idx = p * 256 + tid;
    int row = idx >> 4, c = idx & 15;
    int cph = c ^ (((row >> 2) & 3) << 2);
    bf16x8 v = *(const bf16x8*)(ep + row * 256 + (cph << 4));
    *(bf16x8*)(Gi + (size_t)(mb * 128 + row) * 4096 + nb * 128 + c * 8) = v;
  }
}

// ---------------------------------------------------------------------------
// step: 64x64 tile (16 j x 4 gates), grid 1024, 4 blocks/CU, 16 waves/CU.
// A = decayed h (bf16, pre-swizzled (b&7)<<3), B = WcH3. Fused GRU epilogue.
// ---------------------------------------------------------------------------
__global__ __launch_bounds__(256) void step_kernel(
    const bf16* __restrict__ hbs, const float* __restrict__ hf,
    const bf16* __restrict__ WcH3, const float* __restrict__ bias4,
    const bf16* __restrict__ gi, const bf16* __restrict__ gh_next, int is_last,
    float* __restrict__ hf_next, bf16* __restrict__ hbs_next) {
  __shared__ char smem[32768];
  char* As = smem;            // [2][8192]
  char* Bs = smem + 16384;    // [2][8192]
  int tid = threadIdx.x, lane = tid & 63, wid = tid >> 6;
  int wg = ((blockIdx.x & 7) << 7) + (blockIdx.x >> 3);
  int mb = wg & 15, nb = wg >> 4;    // mb fastest: B-tile (128KB) hot across 16 mb; A 2MB fits L2

  const bf16* aA = hbs + ((size_t)(mb * 64 + wid * 8 + (lane >> 3))) * 1024 + (lane & 7) * 8;
  const bf16* aB = WcH3 + (size_t)nb * 65536 + (wid * 8 + (lane >> 3)) * 64 + (lane & 7) * 8;

  // ---- epilogue prefetch (hidden under the GEMM) ----
  int j = nb * 16 + (lane & 15);
  bf16x4 giv[4];
  bf16   ghv[4];
  float  hfv[4];
#pragma unroll
  for (int reg = 0; reg < 4; ++reg) {
    int brow = mb * 64 + wid * 16 + ((lane >> 4) << 2) + reg;
    size_t hb_ = (size_t)brow * 1024 + j;
    giv[reg] = *(const bf16x4*)(gi + ((size_t)brow << 12) + (j << 2));
    ghv[reg] = gh_next[hb_];
    hfv[reg] = hf[hb_];
  }

  f32x4 acc[4];
#pragma unroll
  for (int b = 0; b < 4; ++b)
#pragma unroll
    for (int q = 0; q < 4; ++q) acc[b][q] = 0.f;

#define ST_STAGE(buf, kt)                                                    \
  do {                                                                       \
    GLL16(aA + (kt) * 64,             As + (buf) * 8192 + wid * 1024);       \
    GLL16(aA + 32 * 1024 + (kt) * 64, As + (buf) * 8192 + (wid + 4) * 1024); \
    GLL16(aB + (kt) * 4096,           Bs + (buf) * 8192 + wid * 1024);       \
    GLL16(aB + (kt) * 4096 + 2048,    Bs + (buf) * 8192 + (wid + 4) * 1024); \
  } while (0)

  ST_STAGE(0, 0);
  __syncthreads();
  for (int kt = 0; kt < 16; ++kt) {
    const int cur = kt & 1;
    if (kt < 15) ST_STAGE(cur ^ 1, kt + 1);
#pragma unroll
    for (int kk = 0; kk < 2; ++kk) {
      int kb = kk * 64 + ((lane >> 4) << 4);
      int row = wid * 16 + (lane & 15);
      bf16x8 af = *(const bf16x8*)(As + cur * 8192 + (((row * 128 + kb)) ^ ((row & 7) << 4)));
      bf16x8 bfr[4];
#pragma unroll
      for (int g = 0; g < 4; ++g) {
        int nl = g * 16 + (lane & 15);
        bfr[g] = *(const bf16x8*)(Bs + cur * 8192 + (((nl * 128 + kb)) ^ ((nl & 7) << 4)));
      }
#pragma unroll
      for (int g = 0; g < 4; ++g)
        acc[g] = __builtin_amdgcn_mfma_f32_16x16x32_bf16(af, bfr[g], acc[g], 0, 0, 0);
    }
    __syncthreads();
  }

  // fused GRU epilogue (direct stores)
  float br = bias4[j], bz = bias4[1024 + j], bn = bias4[2048 + j], bh = bias4[3072 + j];
#pragma unroll
  for (int reg = 0; reg < 4; ++reg) {
    int brow = mb * 64 + wid * 16 + ((lane >> 4) << 2) + reg;
    float pr  = acc[0][reg] + (float)giv[reg][0] + br;
    float pz  = acc[1][reg] + (float)giv[reg][1] + bz;
    float pin = acc[2][reg] + (float)giv[reg][2] + bn;
    float phn = acc[3][reg] + bh;
    float r = sigm(pr), z = sigm(pz);
    float nn = tanh_fast(pin + r * phn);
    float hnew = (1.f - z) * nn + z * hfv[reg];
    float gam = is_last ? 1.f : (float)ghv[reg];
    float hd = hnew * gam;
    hf_next[(size_t)brow * 1024 + j] = hd;
    hbs_next[(size_t)brow * 1024 + (j ^ ((brow & 7) << 3))] = (bf16)hd;
  }
}

// ---------------------------------------------------------------------------
// classifier + softmax
// ---------------------------------------------------------------------------
__global__ void cls_kernel(const float* __restrict__ h, const float* __restrict__ w_cls,
                           const float* __restrict__ b_cls, float* __restrict__ out) {
  int wid = threadIdx.x >> 6, lane = threadIdx.x & 63;
  int b = blockIdx.x * 4 + wid;
  const float* hb = h + (size_t)b * 1024;
  float a0 = 0.f, a1 = 0.f;
#pragma unroll
  for (int e = 0; e < 16; ++e) {
    int i = e * 64 + lane;
    float hv = hb[i];
    a0 += hv * w_cls[i];
    a1 += hv * w_cls[1024 + i];
  }
  for (int off = 32; off; off >>= 1) {
    a0 += __shfl_down(a0, off);
    a1 += __shfl_down(a1, off);
  }
  if (lane == 0) {
    float l0 = a0 + b_cls[0], l1 = a1 + b_cls[1];
    float mx = fmaxf(l0, l1);
    float e0 = __expf(l0 - mx), e1 = __expf(l1 - mx);
    float s = e0 + e1;
    out[b * 2]     = e0 / s;
    out[b * 2 + 1] = e1 / s;
  }
}

// ---------------------------------------------------------------------------
extern "C" void kernel_launch(void* const* d_in, const int* in_sizes, int n_in,
                              void* d_out, int out_size, void* d_ws, size_t ws_size,
                              hipStream_t stream) {
  const float* X     = (const float*)d_in[0];
  const float* Msk   = (const float*)d_in[1];
  const float* D     = (const float*)d_in[2];
  const float* Mean  = (const float*)d_in[3];
  const float* L     = (const float*)d_in[4];
  const float* w_gh  = (const float*)d_in[5];
  const float* b_gh  = (const float*)d_in[6];
  const float* w_gx  = (const float*)d_in[7];
  const float* b_gx  = (const float*)d_in[8];
  const float* w_ih  = (const float*)d_in[9];
  const float* w_hh  = (const float*)d_in[10];
  const float* b_ih  = (const float*)d_in[11];
  const float* b_hh  = (const float*)d_in[12];
  const float* w_cls = (const float*)d_in[13];
  const float* b_cls = (const float*)d_in[14];

  char* w = (char*)d_ws;
  bf16*  XRs   = (bf16*)(w);
  bf16*  Dbfs  = (bf16*)(w + 16777216);
  bf16*  GH    = (bf16*)(w + 25690112);
  bf16*  WcX2  = (bf16*)(w + 61341696);
  bf16*  WcH3  = (bf16*)(w + 65536000);
  bf16*  Wgs   = (bf16*)(w + 73924608);
  float* bias4 = (float*)(w + 74448896);
  float* hf0   = (float*)(w + 74465280);
  float* hf1   = (float*)(w + 78659584);
  bf16*  hb0   = (bf16*)(w + 82853888);
  bf16*  hb1   = (bf16*)(w + 84951040);
  bf16*  Gi    = (bf16*)(w + 87048192);

  size_t base = 87048192;
  int GCH = 16;
  while (GCH > 1 && base + (size_t)GCH * 8388608ull > ws_size) GCH >>= 1;

  float* hfp[2] = {hf0, hf1};
  bf16*  hbp[2] = {hb0, hb1};

  hipMemsetAsync(hf0, 0, 4194304, stream);
  hipMemsetAsync(hb0, 0, 2097152, stream);
  wprep_kernel<<<25616, 256, 0, stream>>>(w_ih, w_hh, b_ih, b_hh, w_gh, WcH3, WcX2, Wgs, bias4);

  int t = 0;
  for (int c = 0; c < 4; ++c) {
    int nsl = (c < 3) ? 17 : 16;
    prep_kernel<<<nsl * 1024, 256, 0, stream>>>(X, Msk, D, Mean, L, w_gx, b_gx, XRs, Dbfs, c, nsl);
    gammah_kernel<<<nsl * 64, 256, 0, stream>>>(Dbfs, Wgs, b_gh, GH);
    for (int sub = 0; sub < 16 / GCH; ++sub) {
      gix_kernel<<<GCH * 256, 256, 0, stream>>>(XRs + (size_t)sub * GCH * 524288, WcX2, Gi);
      for (int tl2 = 0; tl2 < GCH; ++tl2, ++t) {
        int tl = sub * GCH + tl2;
        int cur = t & 1, nxt = cur ^ 1;
        step_kernel<<<1024, 256, 0, stream>>>(
            hbp[cur], hfp[cur], WcH3, bias4,
            Gi + (size_t)tl2 * 4194304, GH + (size_t)(tl + 1) * 1048576,
            (t == 63) ? 1 : 0, hfp[nxt], hbp[nxt]);
      }
    }
  }
  cls_kernel<<<256, 256, 0, stream>>>(hfp[0], w_cls, b_cls, (float*)d_out);
}